// Round 16
// baseline (24.265 us; speedup 1.0000x reference)
//
#include <hip/hip_runtime.h>
#include <math.h>

#define NB 1024
#define IC 3
#define HW 32
#define GCH 16
#define ECH 32
#define NE 8
#define NC 100

#define RS 38            // row stride in texels
#define PS 1292          // plane stride (34*38) texels
#define NTX 3876         // total texels (3 planes)

typedef __attribute__((ext_vector_type(8))) short bf16x8;
typedef __attribute__((ext_vector_type(4))) int   int4v;
typedef __attribute__((ext_vector_type(4))) float f32x4;

__device__ inline short f2bf(float f) {   // RNE fp32->bf16
    unsigned u = __float_as_uint(f);
    unsigned r = (u + 0x7FFF + ((u >> 16) & 1)) >> 16;
    return (short)r;
}
__device__ inline float bf2f(short h) {
    return __uint_as_float(((unsigned)(unsigned short)h) << 16);
}

// r15 algorithm at 512 threads/block (8 waves): 4 blocks/CU x 8 waves =
// 32 waves/CU = 100% occupancy (was 50% cap at 256 threads) to hide
// ds_read latency + MFMA chains. Arithmetic bit-identical to r15.
// Image: interleaved (hi,lo) bf16 texels [3][34][38], int per pixel.
// Gate: hi/lo split (3 MFMAs, argmax-exact). Expert: hi-only (2 MFMAs).
__global__ __launch_bounds__(512, 8) void moe_fused_kernel(
    const float* __restrict__ x,     // [1024,3,32,32]
    const float* __restrict__ gcw,   // [16,3,3,3]
    const float* __restrict__ gcb,   // [16]
    const float* __restrict__ glw,   // [8,16]
    const float* __restrict__ glb,   // [8]
    const float* __restrict__ ecw,   // [8,32,3,3,3]
    const float* __restrict__ ecb,   // [8,32]
    const float* __restrict__ elw,   // [8,100,32]
    const float* __restrict__ elb,   // [8,100]
    float* __restrict__ out_final,   // [1024,100]
    float* __restrict__ out_w)       // [1024,8]
{
    __shared__ __align__(16) int xil[NTX];   // 15.5 KB
    __shared__ float red2[8][32];
    __shared__ float pg[GCH];
    __shared__ float pe[ECH];
    __shared__ int s_best;

    const int t = threadIdx.x;
    const int b = blockIdx.x;
    const int lane = t & 63;
    const int wid = t >> 6;          // 0..7
    const int r15 = lane & 15;
    const int kg = lane >> 4;

    // ---- zero all texels (borders stay zero) ----
    for (int i = t; i < NTX / 4; i += 512) ((int4*)xil)[i] = make_int4(0, 0, 0, 0);

    // ---- gate B-fragments (hi+lo), k = kg*8+r, ch = r15 ----
    bf16x8 gbh, gbl;
    #pragma unroll
    for (int r = 0; r < 8; ++r) {
        int k = kg * 8 + r;
        float w = (k < 27) ? gcw[r15 * 27 + k] : 0.f;
        short h = f2bf(w);
        gbh[r] = h;
        gbl[r] = f2bf(w - bf2f(h));
    }
    const float gb = gcb[r15];

    __syncthreads();

    // ---- stage x -> interleaved texels (cols shifted +2) ----
    const float* xb = x + (size_t)b * (IC * HW * HW);
    for (int i = t; i < 768; i += 512) {
        float4 v = ((const float4*)xb)[i];
        int ci = i >> 8, rem = i & 255, row = rem >> 3, x4 = (rem & 7) << 2;
        int T = ci * PS + (row + 1) * RS + x4 + 2;   // even texel index
        short h0 = f2bf(v.x), h1 = f2bf(v.y), h2 = f2bf(v.z), h3 = f2bf(v.w);
        int t0 = (unsigned short)h0 | ((unsigned)(unsigned short)f2bf(v.x - bf2f(h0)) << 16);
        int t1 = (unsigned short)h1 | ((unsigned)(unsigned short)f2bf(v.y - bf2f(h1)) << 16);
        int t2 = (unsigned short)h2 | ((unsigned)(unsigned short)f2bf(v.z - bf2f(h2)) << 16);
        int t3 = (unsigned short)h3 | ((unsigned)(unsigned short)f2bf(v.w - bf2f(h3)) << 16);
        *(int2*)&xil[T]     = make_int2(t0, t1);
        *(int2*)&xil[T + 2] = make_int2(t2, t3);
    }

    // ---- per-lane tap offsets (texels); k>=27 -> 0 (garbage ok, B=0) ----
    int off[8];
    #pragma unroll
    for (int r = 0; r < 8; ++r) {
        int k = kg * 8 + r;
        int ci = (k < 27) ? (k / 9) : 0;
        int r9 = (k < 27) ? (k - 9 * ci) : 0;
        int ky = r9 / 3;
        int kx = r9 - 3 * ky;
        off[r] = (k < 27) ? (ci * PS + ky * RS + kx + 1) : 0;
    }

    __syncthreads();

    // ================= gate pass (hi/lo MFMA), 8 m-tiles/wave =============
    float sg = 0.f;
    #pragma unroll 2
    for (int m = 0; m < 8; ++m) {
        int px = (wid << 7) + (m << 4) + r15;
        int base = (px >> 5) * RS + (px & 31);
        int T0 = xil[base + off[0]], T1 = xil[base + off[1]];
        int T2 = xil[base + off[2]], T3 = xil[base + off[3]];
        int T4 = xil[base + off[4]], T5 = xil[base + off[5]];
        int T6 = xil[base + off[6]], T7 = xil[base + off[7]];
        int4v ahd = { (int)__builtin_amdgcn_perm(T1, T0, 0x05040100u),
                      (int)__builtin_amdgcn_perm(T3, T2, 0x05040100u),
                      (int)__builtin_amdgcn_perm(T5, T4, 0x05040100u),
                      (int)__builtin_amdgcn_perm(T7, T6, 0x05040100u) };
        int4v ald = { (int)__builtin_amdgcn_perm(T1, T0, 0x07060302u),
                      (int)__builtin_amdgcn_perm(T3, T2, 0x07060302u),
                      (int)__builtin_amdgcn_perm(T5, T4, 0x07060302u),
                      (int)__builtin_amdgcn_perm(T7, T6, 0x07060302u) };
        bf16x8 ah = __builtin_bit_cast(bf16x8, ahd);
        bf16x8 al = __builtin_bit_cast(bf16x8, ald);
        f32x4 d = {0.f, 0.f, 0.f, 0.f};
        d = __builtin_amdgcn_mfma_f32_16x16x32_bf16(al, gbh, d, 0, 0, 0);
        d = __builtin_amdgcn_mfma_f32_16x16x32_bf16(ah, gbl, d, 0, 0, 0);
        d = __builtin_amdgcn_mfma_f32_16x16x32_bf16(ah, gbh, d, 0, 0, 0);
        sg += fmaxf(d[0] + gb, 0.f) + fmaxf(d[1] + gb, 0.f) +
              fmaxf(d[2] + gb, 0.f) + fmaxf(d[3] + gb, 0.f);
    }
    {
        float v = sg;
        v += __shfl_xor(v, 16);
        v += __shfl_xor(v, 32);
        if (lane < 16) red2[wid][lane] = v;
    }
    __syncthreads();
    if (t < GCH) {
        float s = 0.f;
        #pragma unroll
        for (int w2 = 0; w2 < 8; ++w2) s += red2[w2][t];
        pg[t] = s * (1.f / 1024.f);
    }
    __syncthreads();

    // ---- gate linear + softmax + argmax (lanes 0..7) ----
    if (t < NE) {
        float acc = glb[t];
        #pragma unroll
        for (int c = 0; c < GCH; ++c) acc += pg[c] * glw[t * GCH + c];
        float m = acc;
        #pragma unroll
        for (int o = 1; o < NE; o <<= 1) m = fmaxf(m, __shfl_xor(m, o));
        float ex = expf(acc - m);
        float s = ex;
        #pragma unroll
        for (int o = 1; o < NE; o <<= 1) s += __shfl_xor(s, o);
        out_w[(size_t)b * NE + t] = ex / s;
        float mv = acc; int mi = t;
        #pragma unroll
        for (int o = 1; o < NE; o <<= 1) {
            float ov = __shfl_xor(mv, o);
            int   oi = __shfl_xor(mi, o);
            if (ov > mv || (ov == mv && oi < mi)) { mv = ov; mi = oi; }
        }
        if (t == 0) s_best = mi;
    }
    __syncthreads();
    const int e = __builtin_amdgcn_readfirstlane(s_best);

    // ================= expert pass (hi-only MFMA) =================
    const float* ewp = ecw + (size_t)e * (ECH * 27);
    const float* ebp = ecb + (size_t)e * ECH;

    bf16x8 bfr0, bfr1;
    #pragma unroll
    for (int r = 0; r < 8; ++r) {
        int k = kg * 8 + r;
        bfr0[r] = f2bf((k < 27) ? ewp[r15 * 27 + k] : 0.f);
        bfr1[r] = f2bf((k < 27) ? ewp[(16 + r15) * 27 + k] : 0.f);
    }
    const float b0 = ebp[r15];
    const float b1 = ebp[16 + r15];

    const short* xs16 = (const short*)xil;
    float s0 = 0.f, s1 = 0.f;
    #pragma unroll 2
    for (int m = 0; m < 8; ++m) {
        int px = (wid << 7) + (m << 4) + r15;
        int base = (px >> 5) * RS + (px & 31);
        bf16x8 a;
        #pragma unroll
        for (int r = 0; r < 8; ++r)
            a[r] = xs16[2 * (base + off[r])];   // hi half of texel
        f32x4 z = {0.f, 0.f, 0.f, 0.f};
        f32x4 d0 = __builtin_amdgcn_mfma_f32_16x16x32_bf16(a, bfr0, z, 0, 0, 0);
        f32x4 d1 = __builtin_amdgcn_mfma_f32_16x16x32_bf16(a, bfr1, z, 0, 0, 0);
        s0 += fmaxf(d0[0] + b0, 0.f) + fmaxf(d0[1] + b0, 0.f) +
              fmaxf(d0[2] + b0, 0.f) + fmaxf(d0[3] + b0, 0.f);
        s1 += fmaxf(d1[0] + b1, 0.f) + fmaxf(d1[1] + b1, 0.f) +
              fmaxf(d1[2] + b1, 0.f) + fmaxf(d1[3] + b1, 0.f);
    }
    {
        float v0 = s0, v1 = s1;
        v0 += __shfl_xor(v0, 16); v0 += __shfl_xor(v0, 32);
        v1 += __shfl_xor(v1, 16); v1 += __shfl_xor(v1, 32);
        if (lane < 16) { red2[wid][lane] = v0; red2[wid][lane + 16] = v1; }
    }
    __syncthreads();
    if (t < ECH) {
        float s = 0.f;
        #pragma unroll
        for (int w2 = 0; w2 < 8; ++w2) s += red2[w2][t];
        pe[t] = s * (1.f / 1024.f);
    }
    __syncthreads();

    // ---- expert linear: 100 outputs ----
    if (t < NC) {
        const float* lw = elw + ((size_t)e * NC + t) * ECH;
        float acc = elb[e * NC + t];
        #pragma unroll
        for (int c = 0; c < ECH; ++c) acc += pe[c] * lw[c];
        out_final[(size_t)b * NC + t] = acc;
    }
}

extern "C" void kernel_launch(void* const* d_in, const int* in_sizes, int n_in,
                              void* d_out, int out_size, void* d_ws, size_t ws_size,
                              hipStream_t stream) {
    const float* x   = (const float*)d_in[0];
    const float* gcw = (const float*)d_in[1];
    const float* gcb = (const float*)d_in[2];
    const float* glw = (const float*)d_in[3];
    const float* glb = (const float*)d_in[4];
    const float* ecw = (const float*)d_in[5];
    const float* ecb = (const float*)d_in[6];
    const float* elw = (const float*)d_in[7];
    const float* elb = (const float*)d_in[8];

    float* out_final = (float*)d_out;             // [1024,100]
    float* out_w     = (float*)d_out + NB * NC;   // [1024,8]

    hipLaunchKernelGGL(moe_fused_kernel, dim3(NB), dim3(512), 0, stream,
                       x, gcw, gcb, glw, glb, ecw, ecb, elw, elb,
                       out_final, out_w);
}

// Round 17
// 20.795 us; speedup vs baseline: 1.1669x; 1.1669x over previous
//
#include <hip/hip_runtime.h>
#include <math.h>

#define NB 1024
#define IC 3
#define HW 32
#define GCH 16
#define ECH 32
#define NE 8
#define NC 100

#define RS 38            // row stride in texels
#define PS 1292          // plane stride (34*38) texels
#define NTX 3876         // total texels (3 planes)

typedef __attribute__((ext_vector_type(8))) short bf16x8;
typedef __attribute__((ext_vector_type(4))) int   int4v;
typedef __attribute__((ext_vector_type(4))) float f32x4;

__device__ inline short f2bf(float f) {   // RNE fp32->bf16
    unsigned u = __float_as_uint(f);
    unsigned r = (u + 0x7FFF + ((u >> 16) & 1)) >> 16;
    return (short)r;
}
__device__ inline float bf2f(short h) {
    return __uint_as_float(((unsigned)(unsigned short)h) << 16);
}

// r15 structure (256 thr — r16 proved 512 regresses) with:
//  - border-only zeroing (rows 0/33 + cols 0,1,34,35), disjoint from the
//    staged interior -> one barrier instead of two, ~700 fewer stores
//  - gate MFMA chain split: {al*gbh -> ah*gbl} || {ah*gbh}, depth 2 + 4 adds
// Image: interleaved (hi,lo) bf16 texels [3][34][38], one int per pixel.
// Gate: hi/lo split (argmax-exact). Expert: hi-only (absmax 0.0078, fixed).
__global__ __launch_bounds__(256) void moe_fused_kernel(
    const float* __restrict__ x,     // [1024,3,32,32]
    const float* __restrict__ gcw,   // [16,3,3,3]
    const float* __restrict__ gcb,   // [16]
    const float* __restrict__ glw,   // [8,16]
    const float* __restrict__ glb,   // [8]
    const float* __restrict__ ecw,   // [8,32,3,3,3]
    const float* __restrict__ ecb,   // [8,32]
    const float* __restrict__ elw,   // [8,100,32]
    const float* __restrict__ elb,   // [8,100]
    float* __restrict__ out_final,   // [1024,100]
    float* __restrict__ out_w)       // [1024,8]
{
    __shared__ __align__(16) int xil[NTX];   // 15.5 KB
    __shared__ float red2[4][32];
    __shared__ float pg[GCH];
    __shared__ float pe[ECH];
    __shared__ int s_best;

    const int t = threadIdx.x;
    const int b = blockIdx.x;
    const int lane = t & 63;
    const int wid = t >> 6;
    const int r15 = lane & 15;
    const int kg = lane >> 4;

    // ---- border-only zeroing (disjoint from staged interior) ----
    // top/bottom rows: 3 planes x 2 rows x 19 int2 = 114 stores
    if (t < 114) {
        int pl = t / 38, rem = t - pl * 38;
        int r2 = rem / 19, c2 = rem - r2 * 19;
        *(int2*)&xil[pl * PS + (r2 ? 33 : 0) * RS + 2 * c2] = make_int2(0, 0);
    }
    // side cols {0,1} and {34,35}, rows 1..32: 3 x 32 x 2 int2 = 192 stores
    if (t < 192) {
        int pl = t / 64, rem = t & 63;
        int row = 1 + (rem >> 1), side = rem & 1;
        *(int2*)&xil[pl * PS + row * RS + (side ? 34 : 0)] = make_int2(0, 0);
    }

    // ---- gate B-fragments (hi+lo), k = kg*8+r, ch = r15 ----
    bf16x8 gbh, gbl;
    #pragma unroll
    for (int r = 0; r < 8; ++r) {
        int k = kg * 8 + r;
        float w = (k < 27) ? gcw[r15 * 27 + k] : 0.f;
        short h = f2bf(w);
        gbh[r] = h;
        gbl[r] = f2bf(w - bf2f(h));
    }
    const float gb = gcb[r15];

    // ---- stage x -> interleaved texels (cols 2..33, rows 1..32) ----
    const float* xb = x + (size_t)b * (IC * HW * HW);
    #pragma unroll
    for (int i3 = 0; i3 < 3; ++i3) {
        int i = t + i3 * 256;
        float4 v = ((const float4*)xb)[i];
        int ci = i >> 8, rem = i & 255, row = rem >> 3, x4 = (rem & 7) << 2;
        int T = ci * PS + (row + 1) * RS + x4 + 2;   // even texel index
        short h0 = f2bf(v.x), h1 = f2bf(v.y), h2 = f2bf(v.z), h3 = f2bf(v.w);
        int t0 = (unsigned short)h0 | ((unsigned)(unsigned short)f2bf(v.x - bf2f(h0)) << 16);
        int t1 = (unsigned short)h1 | ((unsigned)(unsigned short)f2bf(v.y - bf2f(h1)) << 16);
        int t2 = (unsigned short)h2 | ((unsigned)(unsigned short)f2bf(v.z - bf2f(h2)) << 16);
        int t3 = (unsigned short)h3 | ((unsigned)(unsigned short)f2bf(v.w - bf2f(h3)) << 16);
        *(int2*)&xil[T]     = make_int2(t0, t1);
        *(int2*)&xil[T + 2] = make_int2(t2, t3);
    }

    // ---- per-lane tap offsets (texels); k>=27 -> 0 (in-bounds, B=0) ----
    int off[8];
    #pragma unroll
    for (int r = 0; r < 8; ++r) {
        int k = kg * 8 + r;
        int ci = (k < 27) ? (k / 9) : 0;
        int r9 = (k < 27) ? (k - 9 * ci) : 0;
        int ky = r9 / 3;
        int kx = r9 - 3 * ky;
        off[r] = (k < 27) ? (ci * PS + ky * RS + kx + 1) : 0;
    }

    __syncthreads();

    // ================= gate pass (hi/lo MFMA, split chains) ===============
    float sg = 0.f;
    #pragma unroll 2
    for (int m = 0; m < 16; ++m) {
        int px = (wid << 8) + (m << 4) + r15;
        int base = (px >> 5) * RS + (px & 31);
        int T0 = xil[base + off[0]], T1 = xil[base + off[1]];
        int T2 = xil[base + off[2]], T3 = xil[base + off[3]];
        int T4 = xil[base + off[4]], T5 = xil[base + off[5]];
        int T6 = xil[base + off[6]], T7 = xil[base + off[7]];
        int4v ahd = { (int)__builtin_amdgcn_perm(T1, T0, 0x05040100u),
                      (int)__builtin_amdgcn_perm(T3, T2, 0x05040100u),
                      (int)__builtin_amdgcn_perm(T5, T4, 0x05040100u),
                      (int)__builtin_amdgcn_perm(T7, T6, 0x05040100u) };
        int4v ald = { (int)__builtin_amdgcn_perm(T1, T0, 0x07060302u),
                      (int)__builtin_amdgcn_perm(T3, T2, 0x07060302u),
                      (int)__builtin_amdgcn_perm(T5, T4, 0x07060302u),
                      (int)__builtin_amdgcn_perm(T7, T6, 0x07060302u) };
        bf16x8 ah = __builtin_bit_cast(bf16x8, ahd);
        bf16x8 al = __builtin_bit_cast(bf16x8, ald);
        f32x4 z = {0.f, 0.f, 0.f, 0.f};
        f32x4 d1 = __builtin_amdgcn_mfma_f32_16x16x32_bf16(al, gbh, z, 0, 0, 0);
        d1 = __builtin_amdgcn_mfma_f32_16x16x32_bf16(ah, gbl, d1, 0, 0, 0);
        f32x4 d2 = __builtin_amdgcn_mfma_f32_16x16x32_bf16(ah, gbh, z, 0, 0, 0);
        sg += fmaxf(d1[0] + d2[0] + gb, 0.f) + fmaxf(d1[1] + d2[1] + gb, 0.f) +
              fmaxf(d1[2] + d2[2] + gb, 0.f) + fmaxf(d1[3] + d2[3] + gb, 0.f);
    }
    {
        float v = sg;
        v += __shfl_xor(v, 16);
        v += __shfl_xor(v, 32);
        if (lane < 16) red2[wid][lane] = v;
    }
    __syncthreads();
    if (t < GCH)
        pg[t] = (red2[0][t] + red2[1][t] + red2[2][t] + red2[3][t]) * (1.f / 1024.f);
    __syncthreads();

    // ---- gate linear + softmax + argmax (lanes 0..7) ----
    if (t < NE) {
        float acc = glb[t];
        #pragma unroll
        for (int c = 0; c < GCH; ++c) acc += pg[c] * glw[t * GCH + c];
        float m = acc;
        #pragma unroll
        for (int o = 1; o < NE; o <<= 1) m = fmaxf(m, __shfl_xor(m, o));
        float ex = expf(acc - m);
        float s = ex;
        #pragma unroll
        for (int o = 1; o < NE; o <<= 1) s += __shfl_xor(s, o);
        out_w[(size_t)b * NE + t] = ex / s;
        float mv = acc; int mi = t;
        #pragma unroll
        for (int o = 1; o < NE; o <<= 1) {
            float ov = __shfl_xor(mv, o);
            int   oi = __shfl_xor(mi, o);
            if (ov > mv || (ov == mv && oi < mi)) { mv = ov; mi = oi; }
        }
        if (t == 0) s_best = mi;
    }
    __syncthreads();
    const int e = __builtin_amdgcn_readfirstlane(s_best);

    // ================= expert pass (hi-only MFMA) =================
    const float* ewp = ecw + (size_t)e * (ECH * 27);
    const float* ebp = ecb + (size_t)e * ECH;

    bf16x8 bfr0, bfr1;
    #pragma unroll
    for (int r = 0; r < 8; ++r) {
        int k = kg * 8 + r;
        bfr0[r] = f2bf((k < 27) ? ewp[r15 * 27 + k] : 0.f);
        bfr1[r] = f2bf((k < 27) ? ewp[(16 + r15) * 27 + k] : 0.f);
    }
    const float b0 = ebp[r15];
    const float b1 = ebp[16 + r15];

    const short* xs16 = (const short*)xil;
    float s0 = 0.f, s1 = 0.f;
    #pragma unroll 2
    for (int m = 0; m < 16; ++m) {
        int px = (wid << 8) + (m << 4) + r15;
        int base = (px >> 5) * RS + (px & 31);
        bf16x8 a;
        #pragma unroll
        for (int r = 0; r < 8; ++r)
            a[r] = xs16[2 * (base + off[r])];   // hi half of texel
        f32x4 z = {0.f, 0.f, 0.f, 0.f};
        f32x4 d0 = __builtin_amdgcn_mfma_f32_16x16x32_bf16(a, bfr0, z, 0, 0, 0);
        f32x4 d1 = __builtin_amdgcn_mfma_f32_16x16x32_bf16(a, bfr1, z, 0, 0, 0);
        s0 += fmaxf(d0[0] + b0, 0.f) + fmaxf(d0[1] + b0, 0.f) +
              fmaxf(d0[2] + b0, 0.f) + fmaxf(d0[3] + b0, 0.f);
        s1 += fmaxf(d1[0] + b1, 0.f) + fmaxf(d1[1] + b1, 0.f) +
              fmaxf(d1[2] + b1, 0.f) + fmaxf(d1[3] + b1, 0.f);
    }
    {
        float v0 = s0, v1 = s1;
        v0 += __shfl_xor(v0, 16); v0 += __shfl_xor(v0, 32);
        v1 += __shfl_xor(v1, 16); v1 += __shfl_xor(v1, 32);
        if (lane < 16) { red2[wid][lane] = v0; red2[wid][lane + 16] = v1; }
    }
    __syncthreads();
    if (t < ECH)
        pe[t] = (red2[0][t] + red2[1][t] + red2[2][t] + red2[3][t]) * (1.f / 1024.f);
    __syncthreads();

    // ---- expert linear: 100 outputs ----
    if (t < NC) {
        const float* lw = elw + ((size_t)e * NC + t) * ECH;
        float acc = elb[e * NC + t];
        #pragma unroll
        for (int c = 0; c < ECH; ++c) acc += pe[c] * lw[c];
        out_final[(size_t)b * NC + t] = acc;
    }
}

extern "C" void kernel_launch(void* const* d_in, const int* in_sizes, int n_in,
                              void* d_out, int out_size, void* d_ws, size_t ws_size,
                              hipStream_t stream) {
    const float* x   = (const float*)d_in[0];
    const float* gcw = (const float*)d_in[1];
    const float* gcb = (const float*)d_in[2];
    const float* glw = (const float*)d_in[3];
    const float* glb = (const float*)d_in[4];
    const float* ecw = (const float*)d_in[5];
    const float* ecb = (const float*)d_in[6];
    const float* elw = (const float*)d_in[7];
    const float* elb = (const float*)d_in[8];

    float* out_final = (float*)d_out;             // [1024,100]
    float* out_w     = (float*)d_out + NB * NC;   // [1024,8]

    hipLaunchKernelGGL(moe_fused_kernel, dim3(NB), dim3(256), 0, stream,
                       x, gcw, gcb, glw, glb, ecw, ecb, elw, elb,
                       out_final, out_w);
}

// Round 18
// 19.799 us; speedup vs baseline: 1.2256x; 1.0503x over previous
//
#include <hip/hip_runtime.h>
#include <math.h>

#define NB 1024
#define IC 3
#define HW 32
#define GCH 16
#define ECH 32
#define NE 8
#define NC 100

#define CS 38            // plane (ci) stride in texels
#define RS2 114          // row stride (3 planes interleaved per row)
#define NTX 3876         // 34 rows * 114

typedef __attribute__((ext_vector_type(8))) short bf16x8;
typedef __attribute__((ext_vector_type(4))) int   int4v;
typedef __attribute__((ext_vector_type(4))) float f32x4;

__device__ inline short f2bf(float f) {   // RNE fp32->bf16
    unsigned u = __float_as_uint(f);
    unsigned r = (u + 0x7FFF + ((u >> 16) & 1)) >> 16;
    return (short)r;
}
__device__ inline float bf2f(short h) {
    return __uint_as_float(((unsigned)(unsigned short)h) << 16);
}

// Layout [row][ci][col] (row stride 114, plane stride 38): each lane's 8
// conv taps sit at WAVE-UNIFORM immediate offsets {0,1,2,114,115,116,228,229}
// from vA = rowbase + kg*38 -> compiler merges into ds_read2_b32 (8 -> ~6
// LDS instrs/fragment). k-relabel: kg0..2 = taps 0..7 of plane kg; kg3 =
// leftover (ky2,kx2) taps of the 3 planes at vB+{2,40,78}; pads k>=27 have
// B=0 so kg3's junk slots r>=3 are harmless. A/B share the k-map (permutation
// self-cancels). Gate hi/lo split (argmax-exact); expert hi-only.
__global__ __launch_bounds__(256) void moe_fused_kernel(
    const float* __restrict__ x,     // [1024,3,32,32]
    const float* __restrict__ gcw,   // [16,3,3,3]
    const float* __restrict__ gcb,   // [16]
    const float* __restrict__ glw,   // [8,16]
    const float* __restrict__ glb,   // [8]
    const float* __restrict__ ecw,   // [8,32,3,3,3]
    const float* __restrict__ ecb,   // [8,32]
    const float* __restrict__ elw,   // [8,100,32]
    const float* __restrict__ elb,   // [8,100]
    float* __restrict__ out_final,   // [1024,100]
    float* __restrict__ out_w)       // [1024,8]
{
    __shared__ __align__(16) int xil[NTX];   // 15.5 KB interleaved texels
    __shared__ float red2[4][32];
    __shared__ float pg[GCH];
    __shared__ float pe[ECH];
    __shared__ int s_best;

    const int t = threadIdx.x;
    const int b = blockIdx.x;
    const int lane = t & 63;
    const int wid = t >> 6;
    const int r15 = lane & 15;
    const int kg = lane >> 4;
    const bool k3 = (kg == 3);
    const int kgoff = k3 ? 0 : kg * CS;   // kg3 aliases kg0 (broadcast, junk)

    // ---- zero all texels (borders stay zero) ----
    for (int i = t; i < NTX / 4; i += 256) ((int4*)xil)[i] = make_int4(0, 0, 0, 0);

    // ---- gate B-fragments (hi+lo) under the new k-map ----
    bf16x8 gbh, gbl;
    #pragma unroll
    for (int r = 0; r < 8; ++r) {
        float w = 0.f;
        if (kg < 3) w = gcw[r15 * 27 + kg * 9 + r];
        else if (r < 3) w = gcw[r15 * 27 + r * 9 + 8];
        short h = f2bf(w);
        gbh[r] = h;
        gbl[r] = f2bf(w - bf2f(h));
    }
    const float gb = gcb[r15];

    __syncthreads();

    // ---- stage x -> interleaved texels: (row+1)*114 + ci*38 + col+2 ----
    const float* xb = x + (size_t)b * (IC * HW * HW);
    #pragma unroll
    for (int i3 = 0; i3 < 3; ++i3) {
        int i = t + i3 * 256;
        float4 v = ((const float4*)xb)[i];
        int ci = i >> 8, rem = i & 255, row = rem >> 3, x4 = (rem & 7) << 2;
        int T = (row + 1) * RS2 + ci * CS + x4 + 2;   // even -> b64 aligned
        short h0 = f2bf(v.x), h1 = f2bf(v.y), h2 = f2bf(v.z), h3 = f2bf(v.w);
        int t0 = (unsigned short)h0 | ((unsigned)(unsigned short)f2bf(v.x - bf2f(h0)) << 16);
        int t1 = (unsigned short)h1 | ((unsigned)(unsigned short)f2bf(v.y - bf2f(h1)) << 16);
        int t2 = (unsigned short)h2 | ((unsigned)(unsigned short)f2bf(v.z - bf2f(h2)) << 16);
        int t3 = (unsigned short)h3 | ((unsigned)(unsigned short)f2bf(v.w - bf2f(h3)) << 16);
        *(int2*)&xil[T]     = make_int2(t0, t1);
        *(int2*)&xil[T + 2] = make_int2(t2, t3);
    }

    __syncthreads();

    // ================= gate pass (hi/lo MFMA) =================
    float sg = 0.f;
    #pragma unroll 2
    for (int m = 0; m < 16; ++m) {
        int px = (wid << 8) + (m << 4) + r15;
        int rowbase = (px >> 5) * RS2 + (px & 31) + 1;
        int vA = rowbase + kgoff;
        int vB = rowbase + 2 * RS2;
        int T0 = xil[vA];           int T1 = xil[vA + 1];
        int T2 = xil[vA + 2];       int T3 = xil[vA + RS2];
        int T4 = xil[vA + RS2 + 1]; int T5 = xil[vA + RS2 + 2];
        int T6 = xil[vA + 2 * RS2]; int T7 = xil[vA + 2 * RS2 + 1];
        int U0 = xil[vB + 2];       int U1 = xil[vB + 2 + CS];
        int U2 = xil[vB + 2 + 2 * CS];
        int X0 = k3 ? U0 : T0;
        int X1 = k3 ? U1 : T1;
        int X2 = k3 ? U2 : T2;
        int4v ahd = { (int)__builtin_amdgcn_perm(X1, X0, 0x05040100u),
                      (int)__builtin_amdgcn_perm(T3, X2, 0x05040100u),
                      (int)__builtin_amdgcn_perm(T5, T4, 0x05040100u),
                      (int)__builtin_amdgcn_perm(T7, T6, 0x05040100u) };
        int4v ald = { (int)__builtin_amdgcn_perm(X1, X0, 0x07060302u),
                      (int)__builtin_amdgcn_perm(T3, X2, 0x07060302u),
                      (int)__builtin_amdgcn_perm(T5, T4, 0x07060302u),
                      (int)__builtin_amdgcn_perm(T7, T6, 0x07060302u) };
        bf16x8 ah = __builtin_bit_cast(bf16x8, ahd);
        bf16x8 al = __builtin_bit_cast(bf16x8, ald);
        f32x4 d = {0.f, 0.f, 0.f, 0.f};
        d = __builtin_amdgcn_mfma_f32_16x16x32_bf16(al, gbh, d, 0, 0, 0);
        d = __builtin_amdgcn_mfma_f32_16x16x32_bf16(ah, gbl, d, 0, 0, 0);
        d = __builtin_amdgcn_mfma_f32_16x16x32_bf16(ah, gbh, d, 0, 0, 0);
        sg += fmaxf(d[0] + gb, 0.f) + fmaxf(d[1] + gb, 0.f) +
              fmaxf(d[2] + gb, 0.f) + fmaxf(d[3] + gb, 0.f);
    }
    {
        float v = sg;
        v += __shfl_xor(v, 16);
        v += __shfl_xor(v, 32);
        if (lane < 16) red2[wid][lane] = v;
    }
    __syncthreads();
    if (t < GCH)
        pg[t] = (red2[0][t] + red2[1][t] + red2[2][t] + red2[3][t]) * (1.f / 1024.f);
    __syncthreads();

    // ---- gate linear + softmax + argmax (lanes 0..7) ----
    if (t < NE) {
        float acc = glb[t];
        #pragma unroll
        for (int c = 0; c < GCH; ++c) acc += pg[c] * glw[t * GCH + c];
        float m = acc;
        #pragma unroll
        for (int o = 1; o < NE; o <<= 1) m = fmaxf(m, __shfl_xor(m, o));
        float ex = expf(acc - m);
        float s = ex;
        #pragma unroll
        for (int o = 1; o < NE; o <<= 1) s += __shfl_xor(s, o);
        out_w[(size_t)b * NE + t] = ex / s;
        float mv = acc; int mi = t;
        #pragma unroll
        for (int o = 1; o < NE; o <<= 1) {
            float ov = __shfl_xor(mv, o);
            int   oi = __shfl_xor(mi, o);
            if (ov > mv || (ov == mv && oi < mi)) { mv = ov; mi = oi; }
        }
        if (t == 0) s_best = mi;
    }
    __syncthreads();
    const int e = __builtin_amdgcn_readfirstlane(s_best);

    // ================= expert pass (hi-only MFMA) =================
    const float* ewp = ecw + (size_t)e * (ECH * 27);
    const float* ebp = ecb + (size_t)e * ECH;

    bf16x8 bfr0, bfr1;
    #pragma unroll
    for (int r = 0; r < 8; ++r) {
        float w0 = 0.f, w1 = 0.f;
        if (kg < 3) {
            w0 = ewp[r15 * 27 + kg * 9 + r];
            w1 = ewp[(16 + r15) * 27 + kg * 9 + r];
        } else if (r < 3) {
            w0 = ewp[r15 * 27 + r * 9 + 8];
            w1 = ewp[(16 + r15) * 27 + r * 9 + 8];
        }
        bfr0[r] = f2bf(w0);
        bfr1[r] = f2bf(w1);
    }
    const float b0 = ebp[r15];
    const float b1 = ebp[16 + r15];

    float s0 = 0.f, s1 = 0.f;
    #pragma unroll 2
    for (int m = 0; m < 16; ++m) {
        int px = (wid << 8) + (m << 4) + r15;
        int rowbase = (px >> 5) * RS2 + (px & 31) + 1;
        int vA = rowbase + kgoff;
        int vB = rowbase + 2 * RS2;
        int T0 = xil[vA];           int T1 = xil[vA + 1];
        int T2 = xil[vA + 2];       int T3 = xil[vA + RS2];
        int T4 = xil[vA + RS2 + 1]; int T5 = xil[vA + RS2 + 2];
        int T6 = xil[vA + 2 * RS2]; int T7 = xil[vA + 2 * RS2 + 1];
        int U0 = xil[vB + 2];       int U1 = xil[vB + 2 + CS];
        int U2 = xil[vB + 2 + 2 * CS];
        int X0 = k3 ? U0 : T0;
        int X1 = k3 ? U1 : T1;
        int X2 = k3 ? U2 : T2;
        int4v ahd = { (int)__builtin_amdgcn_perm(X1, X0, 0x05040100u),
                      (int)__builtin_amdgcn_perm(T3, X2, 0x05040100u),
                      (int)__builtin_amdgcn_perm(T5, T4, 0x05040100u),
                      (int)__builtin_amdgcn_perm(T7, T6, 0x05040100u) };
        bf16x8 a = __builtin_bit_cast(bf16x8, ahd);
        f32x4 z = {0.f, 0.f, 0.f, 0.f};
        f32x4 d0 = __builtin_amdgcn_mfma_f32_16x16x32_bf16(a, bfr0, z, 0, 0, 0);
        f32x4 d1 = __builtin_amdgcn_mfma_f32_16x16x32_bf16(a, bfr1, z, 0, 0, 0);
        s0 += fmaxf(d0[0] + b0, 0.f) + fmaxf(d0[1] + b0, 0.f) +
              fmaxf(d0[2] + b0, 0.f) + fmaxf(d0[3] + b0, 0.f);
        s1 += fmaxf(d1[0] + b1, 0.f) + fmaxf(d1[1] + b1, 0.f) +
              fmaxf(d1[2] + b1, 0.f) + fmaxf(d1[3] + b1, 0.f);
    }
    {
        float v0 = s0, v1 = s1;
        v0 += __shfl_xor(v0, 16); v0 += __shfl_xor(v0, 32);
        v1 += __shfl_xor(v1, 16); v1 += __shfl_xor(v1, 32);
        if (lane < 16) { red2[wid][lane] = v0; red2[wid][lane + 16] = v1; }
    }
    __syncthreads();
    if (t < ECH)
        pe[t] = (red2[0][t] + red2[1][t] + red2[2][t] + red2[3][t]) * (1.f / 1024.f);
    __syncthreads();

    // ---- expert linear: 100 outputs ----
    if (t < NC) {
        const float* lw = elw + ((size_t)e * NC + t) * ECH;
        float acc = elb[e * NC + t];
        #pragma unroll
        for (int c = 0; c < ECH; ++c) acc += pe[c] * lw[c];
        out_final[(size_t)b * NC + t] = acc;
    }
}

extern "C" void kernel_launch(void* const* d_in, const int* in_sizes, int n_in,
                              void* d_out, int out_size, void* d_ws, size_t ws_size,
                              hipStream_t stream) {
    const float* x   = (const float*)d_in[0];
    const float* gcw = (const float*)d_in[1];
    const float* gcb = (const float*)d_in[2];
    const float* glw = (const float*)d_in[3];
    const float* glb = (const float*)d_in[4];
    const float* ecw = (const float*)d_in[5];
    const float* ecb = (const float*)d_in[6];
    const float* elw = (const float*)d_in[7];
    const float* elb = (const float*)d_in[8];

    float* out_final = (float*)d_out;             // [1024,100]
    float* out_w     = (float*)d_out + NB * NC;   // [1024,8]

    hipLaunchKernelGGL(moe_fused_kernel, dim3(NB), dim3(256), 0, stream,
                       x, gcw, gcb, glw, glb, ecw, ecb, elw, elb,
                       out_final, out_w);
}